// Round 3
// baseline (677.925 us; speedup 1.0000x reference)
//
#include <hip/hip_runtime.h>
#include <hip/hip_bf16.h>

// NTM cell forward: T=512, B=32, D=1024, N=128.
// Dtype-ADAPTIVE: device-side probe of x decides f32 vs bf16 I/O (wave-uniform
// branch, identical work every call -> graph-capture safe).
// Phase 1: C[t*B+b][5*128] = x @ [Wk|Wv|Wq|We|Ww]^T  (f32, in d_ws, 41.94 MB)
//   f32 inputs: split-bf16 (v = hi + lo) x 3 MFMAs, rel err ~2^-16.
// Phase 2: scan — one 32-lane group per S-row, S in registers, no barriers.

typedef __attribute__((ext_vector_type(8))) short bf16x8;
typedef __attribute__((ext_vector_type(4))) float f32x4;

static constexpr int T_STEPS = 512;
static constexpr int BATCH   = 32;
static constexpr int DDIM    = 1024;
static constexpr int NDIM    = 128;
static constexpr int LDC     = 5 * NDIM;  // 640

// Probe: first 64 words of x as f32. N(0,1) f32 -> exponent in [90,150]
// for essentially all elements; two packed bf16s reinterpreted as f32 have
// exponent ~[214..255]u[0..3]. Wave-uniform result.
__device__ __forceinline__ bool detect_f32_mode(const void* x) {
    const unsigned* xw = (const unsigned*)x;
    unsigned w = xw[threadIdx.x & 63];
    unsigned e = (w >> 23) & 0xFFu;
    unsigned long long m = __ballot(e >= 90u && e <= 150u);
    return __popcll(m) >= 32;
}

// truncate-split: v ~= hi + lo, both bf16 (raw short bits)
__device__ __forceinline__ void split2(float v, short& hi, short& lo) {
    unsigned u  = __builtin_bit_cast(unsigned, v);
    unsigned uh = u & 0xFFFF0000u;
    hi = (short)(uh >> 16);
    float d = v - __builtin_bit_cast(float, uh);
    lo = (short)(__builtin_bit_cast(unsigned, d) >> 16);
}

// ---------------- Phase 1: projection GEMM ----------------
// Grid (128, 5), block 256 = 4 waves, each wave a 64x64 C-subtile.
// Fragment layouts (learn_hip m89/m120 verified):
//   A: lane holds A[m=lane&15][k=(lane>>4)*8+j]; B from row-major W same way.
//   D: col = lane&15, row = (lane>>4)*4 + reg
__global__ __launch_bounds__(256) void proj_gemm_kernel(
    const void* __restrict__ xv,
    const void* __restrict__ w0, const void* __restrict__ w1,
    const void* __restrict__ w2, const void* __restrict__ w3,
    const void* __restrict__ w4,
    float* __restrict__ C)
{
    const void* Ws[5] = {w0, w1, w2, w3, w4};
    const int bm = blockIdx.x, bn = blockIdx.y;
    const int tid  = threadIdx.x;
    const int wave = tid >> 6, lane = tid & 63;
    const int quad = lane >> 4, l16 = lane & 15;
    const int wm = (wave >> 1) * 64, wn = (wave & 1) * 64;
    const int m0 = bm * 128 + wm;

    const bool f32mode = detect_f32_mode(xv);

    f32x4 acc[4][4];
#pragma unroll
    for (int i = 0; i < 4; ++i)
#pragma unroll
        for (int j = 0; j < 4; ++j) acc[i][j] = (f32x4)(0.0f);

    if (f32mode) {
        const float* xs = (const float*)xv;
        const float* ws = (const float*)Ws[bn];
        const float* ap[4]; const float* bp[4];
#pragma unroll
        for (int i = 0; i < 4; ++i) {
            ap[i] = xs + (size_t)(m0 + i * 16 + l16) * DDIM + quad * 8;
            bp[i] = ws + (size_t)(wn + i * 16 + l16) * DDIM + quad * 8;
        }
        for (int kk = 0; kk < DDIM / 32; ++kk) {
            bf16x8 ah[4], al[4], bh[4], bl[4];
#pragma unroll
            for (int i = 0; i < 4; ++i) {
                f32x4 v0 = *(const f32x4*)(ap[i] + kk * 32);
                f32x4 v1 = *(const f32x4*)(ap[i] + kk * 32 + 4);
#pragma unroll
                for (int j = 0; j < 4; ++j) {
                    short h0, l0, h1, l1;
                    split2(v0[j], h0, l0);
                    split2(v1[j], h1, l1);
                    ah[i][j] = h0;     al[i][j] = l0;
                    ah[i][j + 4] = h1; al[i][j + 4] = l1;
                }
                f32x4 u0 = *(const f32x4*)(bp[i] + kk * 32);
                f32x4 u1 = *(const f32x4*)(bp[i] + kk * 32 + 4);
#pragma unroll
                for (int j = 0; j < 4; ++j) {
                    short h0, l0, h1, l1;
                    split2(u0[j], h0, l0);
                    split2(u1[j], h1, l1);
                    bh[i][j] = h0;     bl[i][j] = l0;
                    bh[i][j + 4] = h1; bl[i][j + 4] = l1;
                }
            }
#pragma unroll
            for (int mi = 0; mi < 4; ++mi)
#pragma unroll
                for (int ni = 0; ni < 4; ++ni) {
                    acc[mi][ni] = __builtin_amdgcn_mfma_f32_16x16x32_bf16(
                        ah[mi], bh[ni], acc[mi][ni], 0, 0, 0);
                    acc[mi][ni] = __builtin_amdgcn_mfma_f32_16x16x32_bf16(
                        ah[mi], bl[ni], acc[mi][ni], 0, 0, 0);
                    acc[mi][ni] = __builtin_amdgcn_mfma_f32_16x16x32_bf16(
                        al[mi], bh[ni], acc[mi][ni], 0, 0, 0);
                }
        }
    } else {
        const short* xs = (const short*)xv;
        const short* ws = (const short*)Ws[bn];
        const bf16x8* ap[4]; const bf16x8* bp[4];
#pragma unroll
        for (int i = 0; i < 4; ++i) {
            ap[i] = (const bf16x8*)(xs + (size_t)(m0 + i * 16 + l16) * DDIM + quad * 8);
            bp[i] = (const bf16x8*)(ws + (size_t)(wn + i * 16 + l16) * DDIM + quad * 8);
        }
        for (int kk = 0; kk < DDIM / 32; ++kk) {
            bf16x8 a[4], b[4];
#pragma unroll
            for (int i = 0; i < 4; ++i) a[i] = ap[i][kk * 4];
#pragma unroll
            for (int i = 0; i < 4; ++i) b[i] = bp[i][kk * 4];
#pragma unroll
            for (int mi = 0; mi < 4; ++mi)
#pragma unroll
                for (int ni = 0; ni < 4; ++ni)
                    acc[mi][ni] = __builtin_amdgcn_mfma_f32_16x16x32_bf16(
                        a[mi], b[ni], acc[mi][ni], 0, 0, 0);
        }
    }

#pragma unroll
    for (int mi = 0; mi < 4; ++mi)
#pragma unroll
        for (int ni = 0; ni < 4; ++ni) {
            const int row = m0 + mi * 16 + quad * 4;
            const int col = bn * 128 + wn + ni * 16 + l16;
#pragma unroll
            for (int r = 0; r < 4; ++r)
                C[(size_t)(row + r) * LDC + col] = acc[mi][ni][r];
        }
}

// ---------------- Phase 2: recurrent scan ----------------
__device__ __forceinline__ float tanh_fast(float xx) {
    float ex = __builtin_amdgcn_exp2f(xx * 2.8853900817779268f);  // e^(2x)
    float r  = __builtin_amdgcn_rcpf(ex + 1.0f);
    return fmaf(-2.0f, r, 1.0f);
}

__device__ __forceinline__ float ld_f(const float* p)          { return *p; }
__device__ __forceinline__ float ld_f(const __hip_bfloat16* p) { return __bfloat162float(*p); }
__device__ __forceinline__ void  st_f(float* p, float v)          { *p = v; }
__device__ __forceinline__ void  st_f(__hip_bfloat16* p, float v) { *p = __float2bfloat16(v); }

template <typename T>
__device__ __forceinline__ void scan_impl(
    const float* __restrict__ C, const T* __restrict__ S0, T* __restrict__ out,
    int b, int row, int grp)
{
    const int col0 = grp * 4;
    float S[4];
    {
        const T* s0p = S0 + ((size_t)b * NDIM + row) * NDIM + col0;
#pragma unroll
        for (int j = 0; j < 4; ++j) S[j] = ld_f(s0p + j);
    }

    for (int t = 0; t < T_STEPS; ++t) {
        const float* base = C + (size_t)(t * BATCH + b) * LDC;
        f32x4 k4 = *(const f32x4*)(base + col0);             // k[b, col0..]
        f32x4 q4 = *(const f32x4*)(base + 2 * NDIM + col0);  // q[b, col0..]
        float vrow = base[1 * NDIM + row];
        float erow = base[3 * NDIM + row];
        float wrow = base[4 * NDIM + row];

        float ss = k4.x * k4.x + k4.y * k4.y + k4.z * k4.z + k4.w * k4.w;
#pragma unroll
        for (int off = 16; off >= 1; off >>= 1) ss += __shfl_xor(ss, off, 32);
        float inv   = __builtin_amdgcn_rcpf(sqrtf(ss) + 1e-6f);
        float einv  = erow * inv;
        float wvinv = wrow * vrow * inv;

        float acc = 0.0f;
#pragma unroll
        for (int j = 0; j < 4; ++j) {
            // S_new = tanh(S + kn[j]*(w*v - e*S))
            float t0  = fmaf(-einv, S[j], wvinv);
            float pre = fmaf(k4[j], t0, S[j]);
            float sn  = tanh_fast(pre);
            S[j] = sn;
            acc = fmaf(sn, q4[j], acc);
        }
#pragma unroll
        for (int off = 16; off >= 1; off >>= 1) acc += __shfl_xor(acc, off, 32);

        if (grp == 0) {
            // y = Sq * silu(Sq) = Sq^2 * sigmoid(Sq)
            float sg = __builtin_amdgcn_rcpf(
                1.0f + __builtin_amdgcn_exp2f(-acc * 1.4426950408889634f));
            st_f(out + (size_t)(t * BATCH + b) * NDIM + row, acc * acc * sg);
        }
    }

    T* sf = out + (size_t)T_STEPS * BATCH * NDIM
              + ((size_t)b * NDIM + row) * NDIM + col0;
#pragma unroll
    for (int j = 0; j < 4; ++j) st_f(sf + j, S[j]);
}

// Grid (N/8=16, B=32), block 256. Each 32-lane group owns one S-row
// (4 f32/lane). No __syncthreads in the T-loop.
__global__ __launch_bounds__(256) void ntm_scan_kernel(
    const float* __restrict__ C, const void* __restrict__ S0,
    void* __restrict__ out, const void* __restrict__ xprobe)
{
    const bool f32mode = detect_f32_mode(xprobe);
    const int b   = blockIdx.y;
    const int row = blockIdx.x * 8 + (threadIdx.x >> 5);
    const int grp = threadIdx.x & 31;
    if (f32mode)
        scan_impl<float>(C, (const float*)S0, (float*)out, b, row, grp);
    else
        scan_impl<__hip_bfloat16>(C, (const __hip_bfloat16*)S0,
                                  (__hip_bfloat16*)out, b, row, grp);
}

extern "C" void kernel_launch(void* const* d_in, const int* in_sizes, int n_in,
                              void* d_out, int out_size, void* d_ws, size_t ws_size,
                              hipStream_t stream) {
    const void* x  = d_in[0];
    const void* S0 = d_in[1];
    const void* wk = d_in[2];
    const void* wv = d_in[3];
    const void* wq = d_in[4];
    const void* we = d_in[5];
    const void* ww = d_in[6];
    float* C = (float*)d_ws;  // 16384 * 640 * 4 B = 41,943,040 B

    dim3 g1(128, 5), b1(256);
    proj_gemm_kernel<<<g1, b1, 0, stream>>>(x, wk, wv, wq, we, ww, C);

    dim3 g2(NDIM / 8, BATCH), b2(256);
    ntm_scan_kernel<<<g2, b2, 0, stream>>>(C, S0, d_out, x);
}

// Round 4
// 675.861 us; speedup vs baseline: 1.0031x; 1.0031x over previous
//
#include <hip/hip_runtime.h>
#include <hip/hip_bf16.h>

// NTM cell forward: T=512, B=32, D=1024, N=128. All I/O f32 (empirically
// confirmed R1/R3: bf16 read of x NaN'd; f32 path passed, absmax 4.0).
//
// Pipeline (all on `stream`):
//   split_x / split_w : f32 -> (hi,lo) bf16 pair arrays in ws   [if ws fits]
//   gemm_split        : C[t*B+b][5*128] = x @ [Wk|Wv|Wq|We|Ww]^T via 3-MFMA
//                       split-bf16 (rel err ~2^-16), f32 C in ws
//   knorm             : inv[t*B+b] = 1/(||k row|| + eps)         [if ws fits]
//   ntm_scan          : 1 wave (64 lanes) per S-row, S in regs, prefetch t+1

typedef __attribute__((ext_vector_type(8))) short bf16x8;
typedef __attribute__((ext_vector_type(4))) float f32x4;
typedef __attribute__((ext_vector_type(2))) float f32x2;
typedef __attribute__((ext_vector_type(4))) unsigned short u16x4;

static constexpr int T_STEPS = 512;
static constexpr int BATCH   = 32;
static constexpr int DDIM    = 1024;
static constexpr int NDIM    = 128;
static constexpr int LDC     = 5 * NDIM;           // 640
static constexpr int MROWS   = T_STEPS * BATCH;    // 16384

// ws layout (bytes)
static constexpr size_t OFF_C   = 0;                         // 16384*640*4 = 41,943,040
static constexpr size_t OFF_INV = 41943040;                  // 16384*4     = 65,536
static constexpr size_t OFF_XH  = 42008576;                  // 16M*2       = 33,554,432
static constexpr size_t OFF_XL  = 75563008;
static constexpr size_t OFF_WH  = 109117440;                 // 5*128K*2    = 1,310,720
static constexpr size_t OFF_WL  = 110428160;
static constexpr size_t NEED_MIN  = OFF_XH;                  // C + inv
static constexpr size_t NEED_FULL = 111738880;

__device__ __forceinline__ void split2(float v, short& hi, short& lo) {
    unsigned u  = __builtin_bit_cast(unsigned, v);
    unsigned uh = u & 0xFFFF0000u;
    hi = (short)(uh >> 16);
    float d = v - __builtin_bit_cast(float, uh);
    lo = (short)(__builtin_bit_cast(unsigned, d) >> 16);
}

// ---------------- input pre-split ----------------
__global__ __launch_bounds__(256) void split_x_kernel(
    const float* __restrict__ src, unsigned short* __restrict__ hi,
    unsigned short* __restrict__ lo, int n4)
{
    int i = blockIdx.x * blockDim.x + threadIdx.x;
    int stride = gridDim.x * blockDim.x;
    for (; i < n4; i += stride) {
        f32x4 v = ((const f32x4*)src)[i];
        u16x4 h, l;
#pragma unroll
        for (int j = 0; j < 4; ++j) {
            short hh, ll;
            split2(v[j], hh, ll);
            h[j] = (unsigned short)hh; l[j] = (unsigned short)ll;
        }
        ((u16x4*)hi)[i] = h;
        ((u16x4*)lo)[i] = l;
    }
}

__global__ __launch_bounds__(256) void split_w_kernel(
    const float* __restrict__ w0, const float* __restrict__ w1,
    const float* __restrict__ w2, const float* __restrict__ w3,
    const float* __restrict__ w4,
    unsigned short* __restrict__ hi, unsigned short* __restrict__ lo)
{
    const float* Ws[5] = {w0, w1, w2, w3, w4};
    const int wi = blockIdx.y;
    const int i  = blockIdx.x * blockDim.x + threadIdx.x;  // vec4 idx, 32768/w
    f32x4 v = ((const f32x4*)Ws[wi])[i];
    u16x4 h, l;
#pragma unroll
    for (int j = 0; j < 4; ++j) {
        short hh, ll;
        split2(v[j], hh, ll);
        h[j] = (unsigned short)hh; l[j] = (unsigned short)ll;
    }
    ((u16x4*)hi)[wi * 32768 + i] = h;
    ((u16x4*)lo)[wi * 32768 + i] = l;
}

// ---------------- GEMM (pre-split inputs) ----------------
// Grid (128,5), block 256 = 4 waves, each a 64x64 C-subtile.
// MFMA fragment layouts (learn_hip m89/m120 verified):
//   A/B: lane holds [r=lane&15][k=(lane>>4)*8+j]; D: col=lane&15, row=quad*4+reg
__global__ __launch_bounds__(256) void gemm_split_kernel(
    const unsigned short* __restrict__ xh, const unsigned short* __restrict__ xl,
    const unsigned short* __restrict__ wh, const unsigned short* __restrict__ wl,
    float* __restrict__ C)
{
    const int bm = blockIdx.x, bn = blockIdx.y;
    const int tid  = threadIdx.x;
    const int wave = tid >> 6, lane = tid & 63;
    const int quad = lane >> 4, l16 = lane & 15;
    const int wm = (wave >> 1) * 64, wn = (wave & 1) * 64;
    const int m0 = bm * 128 + wm;

    const bf16x8* ahp[4]; const bf16x8* alp[4];
    const bf16x8* bhp[4]; const bf16x8* blp[4];
#pragma unroll
    for (int i = 0; i < 4; ++i) {
        size_t ao = (size_t)(m0 + i * 16 + l16) * DDIM + quad * 8;
        size_t bo = (size_t)bn * 131072 + (size_t)(wn + i * 16 + l16) * DDIM + quad * 8;
        ahp[i] = (const bf16x8*)(xh + ao);
        alp[i] = (const bf16x8*)(xl + ao);
        bhp[i] = (const bf16x8*)(wh + bo);
        blp[i] = (const bf16x8*)(wl + bo);
    }

    f32x4 acc[4][4];
#pragma unroll
    for (int i = 0; i < 4; ++i)
#pragma unroll
        for (int j = 0; j < 4; ++j) acc[i][j] = (f32x4)(0.0f);

    for (int kk = 0; kk < DDIM / 32; ++kk) {
        bf16x8 ah[4], al[4], bh[4], bl[4];
#pragma unroll
        for (int i = 0; i < 4; ++i) {
            ah[i] = ahp[i][kk * 4]; al[i] = alp[i][kk * 4];
            bh[i] = bhp[i][kk * 4]; bl[i] = blp[i][kk * 4];
        }
#pragma unroll
        for (int mi = 0; mi < 4; ++mi)
#pragma unroll
            for (int ni = 0; ni < 4; ++ni) {
                acc[mi][ni] = __builtin_amdgcn_mfma_f32_16x16x32_bf16(
                    ah[mi], bh[ni], acc[mi][ni], 0, 0, 0);
                acc[mi][ni] = __builtin_amdgcn_mfma_f32_16x16x32_bf16(
                    ah[mi], bl[ni], acc[mi][ni], 0, 0, 0);
                acc[mi][ni] = __builtin_amdgcn_mfma_f32_16x16x32_bf16(
                    al[mi], bh[ni], acc[mi][ni], 0, 0, 0);
            }
    }

#pragma unroll
    for (int mi = 0; mi < 4; ++mi)
#pragma unroll
        for (int ni = 0; ni < 4; ++ni) {
            const int row = m0 + mi * 16 + quad * 4;
            const int col = bn * 128 + wn + ni * 16 + l16;
#pragma unroll
            for (int r = 0; r < 4; ++r)
                C[(size_t)(row + r) * LDC + col] = acc[mi][ni][r];
        }
}

// ---------------- GEMM fallback (inline split, ws too small) ----------------
__global__ __launch_bounds__(256) void gemm_inline_kernel(
    const float* __restrict__ xs,
    const float* __restrict__ w0, const float* __restrict__ w1,
    const float* __restrict__ w2, const float* __restrict__ w3,
    const float* __restrict__ w4,
    float* __restrict__ C)
{
    const float* Ws[5] = {w0, w1, w2, w3, w4};
    const int bm = blockIdx.x, bn = blockIdx.y;
    const int tid  = threadIdx.x;
    const int wave = tid >> 6, lane = tid & 63;
    const int quad = lane >> 4, l16 = lane & 15;
    const int wm = (wave >> 1) * 64, wn = (wave & 1) * 64;
    const int m0 = bm * 128 + wm;
    const float* ws = Ws[bn];

    const float* ap[4]; const float* bp[4];
#pragma unroll
    for (int i = 0; i < 4; ++i) {
        ap[i] = xs + (size_t)(m0 + i * 16 + l16) * DDIM + quad * 8;
        bp[i] = ws + (size_t)(wn + i * 16 + l16) * DDIM + quad * 8;
    }
    f32x4 acc[4][4];
#pragma unroll
    for (int i = 0; i < 4; ++i)
#pragma unroll
        for (int j = 0; j < 4; ++j) acc[i][j] = (f32x4)(0.0f);

    for (int kk = 0; kk < DDIM / 32; ++kk) {
        bf16x8 ah[4], al[4], bh[4], bl[4];
#pragma unroll
        for (int i = 0; i < 4; ++i) {
            f32x4 v0 = *(const f32x4*)(ap[i] + kk * 32);
            f32x4 v1 = *(const f32x4*)(ap[i] + kk * 32 + 4);
            f32x4 u0 = *(const f32x4*)(bp[i] + kk * 32);
            f32x4 u1 = *(const f32x4*)(bp[i] + kk * 32 + 4);
#pragma unroll
            for (int j = 0; j < 4; ++j) {
                short h0, l0, h1, l1;
                split2(v0[j], h0, l0); split2(v1[j], h1, l1);
                ah[i][j] = h0;     al[i][j] = l0;
                ah[i][j + 4] = h1; al[i][j + 4] = l1;
                split2(u0[j], h0, l0); split2(u1[j], h1, l1);
                bh[i][j] = h0;     bl[i][j] = l0;
                bh[i][j + 4] = h1; bl[i][j + 4] = l1;
            }
        }
#pragma unroll
        for (int mi = 0; mi < 4; ++mi)
#pragma unroll
            for (int ni = 0; ni < 4; ++ni) {
                acc[mi][ni] = __builtin_amdgcn_mfma_f32_16x16x32_bf16(
                    ah[mi], bh[ni], acc[mi][ni], 0, 0, 0);
                acc[mi][ni] = __builtin_amdgcn_mfma_f32_16x16x32_bf16(
                    ah[mi], bl[ni], acc[mi][ni], 0, 0, 0);
                acc[mi][ni] = __builtin_amdgcn_mfma_f32_16x16x32_bf16(
                    al[mi], bh[ni], acc[mi][ni], 0, 0, 0);
            }
    }
#pragma unroll
    for (int mi = 0; mi < 4; ++mi)
#pragma unroll
        for (int ni = 0; ni < 4; ++ni) {
            const int row = m0 + mi * 16 + quad * 4;
            const int col = bn * 128 + wn + ni * 16 + l16;
#pragma unroll
            for (int r = 0; r < 4; ++r)
                C[(size_t)(row + r) * LDC + col] = acc[mi][ni][r];
        }
}

// ---------------- k-norm precompute ----------------
// inv[r] = 1/(||C[r, 0:128]|| + eps). Grid 2048 blocks x 256 thr: 32-lane
// group per row.
__global__ __launch_bounds__(256) void knorm_kernel(
    const float* __restrict__ C, float* __restrict__ inv)
{
    const int r = blockIdx.x * 8 + (threadIdx.x >> 5);
    const int g = threadIdx.x & 31;
    f32x4 k4 = *(const f32x4*)(C + (size_t)r * LDC + g * 4);
    float ss = k4.x * k4.x + k4.y * k4.y + k4.z * k4.z + k4.w * k4.w;
#pragma unroll
    for (int off = 16; off >= 1; off >>= 1) ss += __shfl_xor(ss, off, 32);
    if (g == 0)
        inv[r] = __builtin_amdgcn_rcpf(sqrtf(ss) + 1e-6f);
}

// ---------------- recurrent scan ----------------
__device__ __forceinline__ float tanh_fast(float xx) {
    float ex = __builtin_amdgcn_exp2f(xx * 2.8853900817779268f);  // e^(2x)
    float r  = __builtin_amdgcn_rcpf(ex + 1.0f);
    return fmaf(-2.0f, r, 1.0f);
}

// Grid (32,32), block 256 = 4 waves; one 64-lane wave per S-row (2 f32/lane).
// 4096 waves -> 16 waves/CU. Next step's loads issued before this step's
// compute chain (t+1 loads don't depend on S).
__global__ __launch_bounds__(256) void ntm_scan_kernel(
    const float* __restrict__ C, const float* __restrict__ invA,
    const float* __restrict__ S0, float* __restrict__ out, int use_inv)
{
    const int b    = blockIdx.y;
    const int row  = blockIdx.x * 4 + (threadIdx.x >> 6);
    const int lane = threadIdx.x & 63;
    const int col0 = lane * 2;

    f32x2 S = *(const f32x2*)(S0 + ((size_t)b * NDIM + row) * NDIM + col0);

    const float* base0 = C + (size_t)b * LDC;
    f32x2 k2 = *(const f32x2*)(base0 + col0);
    f32x2 q2 = *(const f32x2*)(base0 + 2 * NDIM + col0);
    float vr = base0[NDIM + row];
    float er = base0[3 * NDIM + row];
    float wr = base0[4 * NDIM + row];
    float iv = invA[b];

    for (int t = 0; t < T_STEPS; ++t) {
        const int tn = (t + 1 < T_STEPS) ? t + 1 : t;
        const float* bp = C + (size_t)(tn * BATCH + b) * LDC;
        f32x2 k2n = *(const f32x2*)(bp + col0);
        f32x2 q2n = *(const f32x2*)(bp + 2 * NDIM + col0);
        float vrn = bp[NDIM + row];
        float ern = bp[3 * NDIM + row];
        float wrn = bp[4 * NDIM + row];
        float ivn = invA[tn * BATCH + b];

        float inv_t;
        if (use_inv) {
            inv_t = iv;
        } else {
            float ss = k2.x * k2.x + k2.y * k2.y;
#pragma unroll
            for (int off = 32; off >= 1; off >>= 1) ss += __shfl_xor(ss, off, 64);
            inv_t = __builtin_amdgcn_rcpf(sqrtf(ss) + 1e-6f);
        }
        const float einv  = er * inv_t;
        const float wvinv = wr * vr * inv_t;

        // S_new = tanh(S + kn*(w*v - e*S)); acc = S_new . q
        float t0  = fmaf(-einv, S.x, wvinv);
        float pre = fmaf(k2.x, t0, S.x);
        S.x = tanh_fast(pre);
        float acc = S.x * q2.x;
        t0  = fmaf(-einv, S.y, wvinv);
        pre = fmaf(k2.y, t0, S.y);
        S.y = tanh_fast(pre);
        acc = fmaf(S.y, q2.y, acc);
#pragma unroll
        for (int off = 32; off >= 1; off >>= 1) acc += __shfl_xor(acc, off, 64);

        if (lane == 0) {
            float sg = __builtin_amdgcn_rcpf(
                1.0f + __builtin_amdgcn_exp2f(-acc * 1.4426950408889634f));
            out[(size_t)(t * BATCH + b) * NDIM + row] = acc * acc * sg;
        }
        k2 = k2n; q2 = q2n; vr = vrn; er = ern; wr = wrn; iv = ivn;
    }

    *(f32x2*)(out + (size_t)T_STEPS * BATCH * NDIM
              + ((size_t)b * NDIM + row) * NDIM + col0) = S;
}

extern "C" void kernel_launch(void* const* d_in, const int* in_sizes, int n_in,
                              void* d_out, int out_size, void* d_ws, size_t ws_size,
                              hipStream_t stream) {
    const float* x  = (const float*)d_in[0];
    const float* S0 = (const float*)d_in[1];
    const float* wk = (const float*)d_in[2];
    const float* wv = (const float*)d_in[3];
    const float* wq = (const float*)d_in[4];
    const float* we = (const float*)d_in[5];
    const float* ww = (const float*)d_in[6];
    float* out = (float*)d_out;

    char* ws = (char*)d_ws;
    float* C   = (float*)(ws + OFF_C);
    float* inv = (float*)(ws + OFF_INV);
    unsigned short* xh = (unsigned short*)(ws + OFF_XH);
    unsigned short* xl = (unsigned short*)(ws + OFF_XL);
    unsigned short* wh = (unsigned short*)(ws + OFF_WH);
    unsigned short* wl = (unsigned short*)(ws + OFF_WL);

    const bool have_inv = ws_size >= NEED_MIN;   // host-side, constant per harness
    const bool presplit = ws_size >= NEED_FULL;

    if (presplit) {
        split_x_kernel<<<1024, 256, 0, stream>>>(x, xh, xl,
                                                 MROWS * DDIM / 4 /* 4194304 */);
        split_w_kernel<<<dim3(128, 5), 256, 0, stream>>>(wk, wv, wq, we, ww, wh, wl);
        gemm_split_kernel<<<dim3(128, 5), 256, 0, stream>>>(xh, xl, wh, wl, C);
    } else {
        gemm_inline_kernel<<<dim3(128, 5), 256, 0, stream>>>(x, wk, wv, wq, we, ww, C);
    }
    if (have_inv)
        knorm_kernel<<<MROWS / 8, 256, 0, stream>>>(C, inv);

    ntm_scan_kernel<<<dim3(32, 32), 256, 0, stream>>>(
        C, have_inv ? inv : C, S0, out, have_inv ? 1 : 0);
}

// Round 5
// 416.526 us; speedup vs baseline: 1.6276x; 1.6226x over previous
//
#include <hip/hip_runtime.h>
#include <hip/hip_bf16.h>

// NTM cell forward: T=512, B=32, D=1024, N=128. All I/O f32.
// Pipeline: gemm (LDS-staged split-bf16 3-MFMA) -> knorm (k-normalize in
// place, fold w*v into v-slot) -> scan (1 wave/S-row, XCD-affine batches,
// depth-2 prefetch). ws needs only C: 16384*640*4 = 41,943,040 B.

typedef __attribute__((ext_vector_type(8))) short bf16x8;
typedef __attribute__((ext_vector_type(4))) float f32x4;
typedef __attribute__((ext_vector_type(2))) float f32x2;
typedef __attribute__((ext_vector_type(4))) unsigned short u16x4;

static constexpr int T_STEPS = 512;
static constexpr int BATCH   = 32;
static constexpr int DDIM    = 1024;
static constexpr int NDIM    = 128;
static constexpr int LDC     = 5 * NDIM;         // 640
static constexpr int MROWS   = T_STEPS * BATCH;  // 16384

__device__ __forceinline__ void split2(float v, unsigned short& hi, unsigned short& lo) {
    unsigned u  = __builtin_bit_cast(unsigned, v);
    unsigned uh = u & 0xFFFF0000u;
    hi = (unsigned short)(uh >> 16);
    float d = v - __builtin_bit_cast(float, uh);
    lo = (unsigned short)(__builtin_bit_cast(unsigned, d) >> 16);
}

// ---------------- Phase 1: LDS-staged split-bf16 GEMM ----------------
// Grid (128,5), block 256 = 4 waves, 128x128 tile, BK=32.
// LDS row stride 40 bf16 (80 B): 16B-aligned rows, conflict-light frag reads.
// MFMA layouts (verified R3-pass): A/B lane=[r=lane&15][k=quad*8+j];
// D: col=lane&15, row=quad*4+reg.
static constexpr int LSTR = 40;
static constexpr int OAH = 0, OAL = 128 * LSTR, OBH = 2 * 128 * LSTR, OBL = 3 * 128 * LSTR;

__global__ __launch_bounds__(256, 3) void gemm_kernel(
    const float* __restrict__ x,
    const float* __restrict__ w0, const float* __restrict__ w1,
    const float* __restrict__ w2, const float* __restrict__ w3,
    const float* __restrict__ w4,
    float* __restrict__ C)
{
    __shared__ unsigned short lds[4 * 128 * LSTR];  // 40,960 B

    const float* Ws[5] = {w0, w1, w2, w3, w4};
    const int bm = blockIdx.x, bn = blockIdx.y;
    const int tid  = threadIdx.x;
    const int wave = tid >> 6, lane = tid & 63;
    const int quad = lane >> 4, l16 = lane & 15;
    const int wm = (wave >> 1) * 64, wn = (wave & 1) * 64;
    const int m0 = bm * 128;
    const float* wsrc = Ws[bn];

    f32x4 acc[4][4];
#pragma unroll
    for (int i = 0; i < 4; ++i)
#pragma unroll
        for (int j = 0; j < 4; ++j) acc[i][j] = (f32x4)(0.0f);

    const int srow = tid >> 3;        // 0..31 base row (x8 per pass)
    const int sc4  = tid & 7;         // 16B column chunk
    const int fa = (wm + l16) * LSTR + quad * 8;
    const int fb = (wn + l16) * LSTR + quad * 8;

    for (int kk = 0; kk < 32; ++kk) {
        // stage A and B tiles (f32 -> hi/lo bf16), 4 chunks each per thread
#pragma unroll
        for (int i = 0; i < 4; ++i) {
            const int row = srow + i * 32;
            f32x4 va = *(const f32x4*)(x + (size_t)(m0 + row) * DDIM + kk * 32 + sc4 * 4);
            f32x4 vb = *(const f32x4*)(wsrc + (size_t)row * DDIM + kk * 32 + sc4 * 4);
            u16x4 ha, la, hb, lb;
#pragma unroll
            for (int j = 0; j < 4; ++j) {
                unsigned short h, l;
                split2(va[j], h, l); ha[j] = h; la[j] = l;
                split2(vb[j], h, l); hb[j] = h; lb[j] = l;
            }
            const int o = row * LSTR + sc4 * 4;
            *(u16x4*)&lds[OAH + o] = ha;
            *(u16x4*)&lds[OAL + o] = la;
            *(u16x4*)&lds[OBH + o] = hb;
            *(u16x4*)&lds[OBL + o] = lb;
        }
        __syncthreads();

        bf16x8 ah[4], al[4], bh[4], bl[4];
#pragma unroll
        for (int i = 0; i < 4; ++i) {
            ah[i] = *(const bf16x8*)&lds[OAH + fa + i * 16 * LSTR];
            al[i] = *(const bf16x8*)&lds[OAL + fa + i * 16 * LSTR];
            bh[i] = *(const bf16x8*)&lds[OBH + fb + i * 16 * LSTR];
            bl[i] = *(const bf16x8*)&lds[OBL + fb + i * 16 * LSTR];
        }
#pragma unroll
        for (int mi = 0; mi < 4; ++mi)
#pragma unroll
            for (int ni = 0; ni < 4; ++ni) {
                acc[mi][ni] = __builtin_amdgcn_mfma_f32_16x16x32_bf16(
                    ah[mi], bh[ni], acc[mi][ni], 0, 0, 0);
                acc[mi][ni] = __builtin_amdgcn_mfma_f32_16x16x32_bf16(
                    ah[mi], bl[ni], acc[mi][ni], 0, 0, 0);
                acc[mi][ni] = __builtin_amdgcn_mfma_f32_16x16x32_bf16(
                    al[mi], bh[ni], acc[mi][ni], 0, 0, 0);
            }
        __syncthreads();
    }

#pragma unroll
    for (int mi = 0; mi < 4; ++mi)
#pragma unroll
        for (int ni = 0; ni < 4; ++ni) {
            const int row = m0 + wm + mi * 16 + quad * 4;
            const int col = bn * 128 + wn + ni * 16 + l16;
#pragma unroll
            for (int r = 0; r < 4; ++r)
                C[(size_t)(row + r) * LDC + col] = acc[mi][ni][r];
        }
}

// ---------------- knorm prep ----------------
// Per C-row r=(t*B+b): k <- k/(||k||+eps) in place; v-slot <- w*v.
// Grid 4096 x 256 (wave per row).
__global__ __launch_bounds__(256) void knorm_kernel(float* __restrict__ C)
{
    const int r    = blockIdx.x * 4 + (threadIdx.x >> 6);
    const int lane = threadIdx.x & 63;
    float* base = C + (size_t)r * LDC;

    f32x2 k2 = *(const f32x2*)(base + lane * 2);
    f32x2 v2 = *(const f32x2*)(base + NDIM + lane * 2);
    f32x2 w2 = *(const f32x2*)(base + 4 * NDIM + lane * 2);

    float ss = k2.x * k2.x + k2.y * k2.y;
#pragma unroll
    for (int off = 32; off >= 1; off >>= 1) ss += __shfl_xor(ss, off, 64);
    float inv = __builtin_amdgcn_rcpf(sqrtf(ss) + 1e-6f);

    f32x2 kn = {k2.x * inv, k2.y * inv};
    f32x2 wv = {v2.x * w2.x, v2.y * w2.y};
    *(f32x2*)(base + lane * 2) = kn;
    *(f32x2*)(base + NDIM + lane * 2) = wv;
}

// ---------------- recurrent scan ----------------
__device__ __forceinline__ float tanh_fast(float xx) {
    float ex = __builtin_amdgcn_exp2f(xx * 2.8853900817779268f);  // e^(2x)
    float r  = __builtin_amdgcn_rcpf(ex + 1.0f);
    return fmaf(-2.0f, r, 1.0f);
}

// Grid 1024 blocks x 256 thr; 1 wave per S-row (2 f32/lane).
// XCD-affine mapping: all blocks of batch b land on XCD b%8 (round-robin
// dispatch heuristic; perf-only). Depth-2 register prefetch.
__global__ __launch_bounds__(256) void ntm_scan_kernel(
    const float* __restrict__ C, const float* __restrict__ S0,
    float* __restrict__ out)
{
    const int L    = blockIdx.x;          // 0..1023
    const int j    = L >> 3;              // 0..127
    const int b    = (L & 7) + 8 * (j & 3);
    const int row  = (j >> 2) * 4 + (threadIdx.x >> 6);
    const int lane = threadIdx.x & 63;
    const int col0 = lane * 2;

    f32x2 S = *(const f32x2*)(S0 + ((size_t)b * NDIM + row) * NDIM + col0);

    const size_t STRIDE = (size_t)BATCH * LDC;  // floats per timestep
    const float* p0 = C + (size_t)b * LDC;

    f32x2 k_a, q_a, k_b, q_b, k_c, q_c;
    float e_a, wv_a, e_b, wv_b, e_c, wv_c;

    // load(t): kn at 0, wv at NDIM, q at 2*NDIM, e at 3*NDIM
    k_a  = *(const f32x2*)(p0 + col0);
    q_a  = *(const f32x2*)(p0 + 2 * NDIM + col0);
    e_a  = p0[3 * NDIM + row];
    wv_a = p0[NDIM + row];
    const float* p1 = p0 + STRIDE;
    k_b  = *(const f32x2*)(p1 + col0);
    q_b  = *(const f32x2*)(p1 + 2 * NDIM + col0);
    e_b  = p1[3 * NDIM + row];
    wv_b = p1[NDIM + row];

    const float* p_pref = p1 + STRIDE;  // t = 2
    float* op = out + (size_t)b * NDIM + row;

    for (int t = 0; t < T_STEPS; ++t) {
        // prefetch t+2 (clamped to 511)
        k_c  = *(const f32x2*)(p_pref + col0);
        q_c  = *(const f32x2*)(p_pref + 2 * NDIM + col0);
        e_c  = p_pref[3 * NDIM + row];
        wv_c = p_pref[NDIM + row];
        if (t < T_STEPS - 3) p_pref += STRIDE;

        // S_new = tanh(S + kn*(wv - e*S)); acc = S_new . q
        float t0  = fmaf(-e_a, S.x, wv_a);
        float pre = fmaf(k_a.x, t0, S.x);
        S.x = tanh_fast(pre);
        float acc = S.x * q_a.x;
        t0  = fmaf(-e_a, S.y, wv_a);
        pre = fmaf(k_a.y, t0, S.y);
        S.y = tanh_fast(pre);
        acc = fmaf(S.y, q_a.y, acc);
#pragma unroll
        for (int off = 32; off >= 1; off >>= 1) acc += __shfl_xor(acc, off, 64);

        if (lane == 0) {
            float sg = __builtin_amdgcn_rcpf(
                1.0f + __builtin_amdgcn_exp2f(-acc * 1.4426950408889634f));
            *op = acc * acc * sg;
        }
        op += BATCH * NDIM;

        k_a = k_b; q_a = q_b; e_a = e_b; wv_a = wv_b;
        k_b = k_c; q_b = q_c; e_b = e_c; wv_b = wv_c;
    }

    *(f32x2*)(out + (size_t)T_STEPS * BATCH * NDIM
              + ((size_t)b * NDIM + row) * NDIM + col0) = S;
}

extern "C" void kernel_launch(void* const* d_in, const int* in_sizes, int n_in,
                              void* d_out, int out_size, void* d_ws, size_t ws_size,
                              hipStream_t stream) {
    const float* x  = (const float*)d_in[0];
    const float* S0 = (const float*)d_in[1];
    const float* wk = (const float*)d_in[2];
    const float* wv = (const float*)d_in[3];
    const float* wq = (const float*)d_in[4];
    const float* we = (const float*)d_in[5];
    const float* ww = (const float*)d_in[6];
    float* out = (float*)d_out;
    float* C   = (float*)d_ws;  // 41,943,040 B

    gemm_kernel<<<dim3(128, 5), 256, 0, stream>>>(x, wk, wv, wq, we, ww, C);
    knorm_kernel<<<MROWS / 4, 256, 0, stream>>>(C);
    ntm_scan_kernel<<<1024, 256, 0, stream>>>(C, S0, out);
}

// Round 7
// 396.558 us; speedup vs baseline: 1.7095x; 1.0504x over previous
//
#include <hip/hip_runtime.h>
#include <hip/hip_bf16.h>

// NTM cell forward: T=512, B=32, D=1024, N=128. All I/O f32.
// gemm (LDS-staged split-bf16 3-MFMA) -> knorm (k-normalize in place, fold
// w*v into v-slot) -> scan (32-lane group per S-row, 4 f32/lane, DPP-tree
// dot-reduce, XCD-affine batches, depth-2 prefetch).
// ws needs only C: 16384*640*4 = 41,943,040 B.

typedef __attribute__((ext_vector_type(8))) short bf16x8;
typedef __attribute__((ext_vector_type(4))) float f32x4;
typedef __attribute__((ext_vector_type(2))) float f32x2;
typedef __attribute__((ext_vector_type(4))) unsigned short u16x4;

static constexpr int T_STEPS = 512;
static constexpr int BATCH   = 32;
static constexpr int DDIM    = 1024;
static constexpr int NDIM    = 128;
static constexpr int LDC     = 5 * NDIM;         // 640
static constexpr int MROWS   = T_STEPS * BATCH;  // 16384

__device__ __forceinline__ void split2(float v, unsigned short& hi, unsigned short& lo) {
    unsigned u  = __builtin_bit_cast(unsigned, v);
    unsigned uh = u & 0xFFFF0000u;
    hi = (unsigned short)(uh >> 16);
    float d = v - __builtin_bit_cast(float, uh);
    lo = (unsigned short)(__builtin_bit_cast(unsigned, d) >> 16);
}

// ---------------- Phase 1: LDS-staged split-bf16 GEMM (unchanged R5) -------
static constexpr int LSTR = 40;
static constexpr int OAH = 0, OAL = 128 * LSTR, OBH = 2 * 128 * LSTR, OBL = 3 * 128 * LSTR;

__global__ __launch_bounds__(256, 3) void gemm_kernel(
    const float* __restrict__ x,
    const float* __restrict__ w0, const float* __restrict__ w1,
    const float* __restrict__ w2, const float* __restrict__ w3,
    const float* __restrict__ w4,
    float* __restrict__ C)
{
    __shared__ unsigned short lds[4 * 128 * LSTR];  // 40,960 B

    const float* Ws[5] = {w0, w1, w2, w3, w4};
    const int bm = blockIdx.x, bn = blockIdx.y;
    const int tid  = threadIdx.x;
    const int wave = tid >> 6, lane = tid & 63;
    const int quad = lane >> 4, l16 = lane & 15;
    const int wm = (wave >> 1) * 64, wn = (wave & 1) * 64;
    const int m0 = bm * 128;
    const float* wsrc = Ws[bn];

    f32x4 acc[4][4];
#pragma unroll
    for (int i = 0; i < 4; ++i)
#pragma unroll
        for (int j = 0; j < 4; ++j) acc[i][j] = (f32x4)(0.0f);

    const int srow = tid >> 3;
    const int sc4  = tid & 7;
    const int fa = (wm + l16) * LSTR + quad * 8;
    const int fb = (wn + l16) * LSTR + quad * 8;

    for (int kk = 0; kk < 32; ++kk) {
#pragma unroll
        for (int i = 0; i < 4; ++i) {
            const int row = srow + i * 32;
            f32x4 va = *(const f32x4*)(x + (size_t)(m0 + row) * DDIM + kk * 32 + sc4 * 4);
            f32x4 vb = *(const f32x4*)(wsrc + (size_t)row * DDIM + kk * 32 + sc4 * 4);
            u16x4 ha, la, hb, lb;
#pragma unroll
            for (int j = 0; j < 4; ++j) {
                unsigned short h, l;
                split2(va[j], h, l); ha[j] = h; la[j] = l;
                split2(vb[j], h, l); hb[j] = h; lb[j] = l;
            }
            const int o = row * LSTR + sc4 * 4;
            *(u16x4*)&lds[OAH + o] = ha;
            *(u16x4*)&lds[OAL + o] = la;
            *(u16x4*)&lds[OBH + o] = hb;
            *(u16x4*)&lds[OBL + o] = lb;
        }
        __syncthreads();

        bf16x8 ah[4], al[4], bh[4], bl[4];
#pragma unroll
        for (int i = 0; i < 4; ++i) {
            ah[i] = *(const bf16x8*)&lds[OAH + fa + i * 16 * LSTR];
            al[i] = *(const bf16x8*)&lds[OAL + fa + i * 16 * LSTR];
            bh[i] = *(const bf16x8*)&lds[OBH + fb + i * 16 * LSTR];
            bl[i] = *(const bf16x8*)&lds[OBL + fb + i * 16 * LSTR];
        }
#pragma unroll
        for (int mi = 0; mi < 4; ++mi)
#pragma unroll
            for (int ni = 0; ni < 4; ++ni) {
                acc[mi][ni] = __builtin_amdgcn_mfma_f32_16x16x32_bf16(
                    ah[mi], bh[ni], acc[mi][ni], 0, 0, 0);
                acc[mi][ni] = __builtin_amdgcn_mfma_f32_16x16x32_bf16(
                    ah[mi], bl[ni], acc[mi][ni], 0, 0, 0);
                acc[mi][ni] = __builtin_amdgcn_mfma_f32_16x16x32_bf16(
                    al[mi], bh[ni], acc[mi][ni], 0, 0, 0);
            }
        __syncthreads();
    }

#pragma unroll
    for (int mi = 0; mi < 4; ++mi)
#pragma unroll
        for (int ni = 0; ni < 4; ++ni) {
            const int row = m0 + wm + mi * 16 + quad * 4;
            const int col = bn * 128 + wn + ni * 16 + l16;
#pragma unroll
            for (int r = 0; r < 4; ++r)
                C[(size_t)(row + r) * LDC + col] = acc[mi][ni][r];
        }
}

// ---------------- knorm prep (unchanged R5) ----------------
__global__ __launch_bounds__(256) void knorm_kernel(float* __restrict__ C)
{
    const int r    = blockIdx.x * 4 + (threadIdx.x >> 6);
    const int lane = threadIdx.x & 63;
    float* base = C + (size_t)r * LDC;

    f32x2 k2 = *(const f32x2*)(base + lane * 2);
    f32x2 v2 = *(const f32x2*)(base + NDIM + lane * 2);
    f32x2 w2 = *(const f32x2*)(base + 4 * NDIM + lane * 2);

    float ss = k2.x * k2.x + k2.y * k2.y;
#pragma unroll
    for (int off = 32; off >= 1; off >>= 1) ss += __shfl_xor(ss, off, 64);
    float inv = __builtin_amdgcn_rcpf(sqrtf(ss) + 1e-6f);

    f32x2 kn = {k2.x * inv, k2.y * inv};
    f32x2 wv = {v2.x * w2.x, v2.y * w2.y};
    *(f32x2*)(base + lane * 2) = kn;
    *(f32x2*)(base + NDIM + lane * 2) = wv;
}

// ---------------- recurrent scan ----------------
__device__ __forceinline__ float tanh_fast(float xx) {
    float ex = __builtin_amdgcn_exp2f(xx * 2.8853900817779268f);  // e^(2x)
    float r  = __builtin_amdgcn_rcpf(ex + 1.0f);
    return fmaf(-2.0f, r, 1.0f);
}

// x + dpp_perm(x); ctrl/masks must be constant-expressions -> template.
// bound_ctrl=true: invalid source lanes read 0.
template <int CTRL, int RMASK>
__device__ __forceinline__ float dpp_add(float x) {
    int yi = __builtin_amdgcn_update_dpp(
        0, __builtin_bit_cast(int, x), CTRL, RMASK, 0xF, true);
    return x + __builtin_bit_cast(float, yi);
}

// Sum across each 32-lane group (VALU-pipe DPP tree). After this, lanes
// 16..31 (and 48..63) hold their group's full 32-lane sum.
__device__ __forceinline__ float dpp_reduce32(float x) {
    x = dpp_add<0xB1,  0xF>(x);  // quad_perm(1,0,3,2): + lane^1
    x = dpp_add<0x4E,  0xF>(x);  // quad_perm(2,3,0,1): + lane^2
    x = dpp_add<0x141, 0xF>(x);  // row_half_mirror: + lane^4
    x = dpp_add<0x140, 0xF>(x);  // row_mirror: + lane^8
    x = dpp_add<0x142, 0xA>(x);  // row_bcast15: rows 1,3 += row 0,2 sum
    return x;
}

// Grid 512 blocks x 256 thr; 32-lane group per S-row, 4 f32/lane, 2 rows/wave.
// Batch -> XCD-affine (b%8 == blockIdx%8, round-robin dispatch heuristic).
// Depth-2 register prefetch. C row layout: [kn | w*v | q | e | (w)].
__global__ __launch_bounds__(256) void ntm_scan_kernel(
    const float* __restrict__ C, const float* __restrict__ S0,
    float* __restrict__ out)
{
    const int L    = blockIdx.x;            // 0..511
    const int b    = (L & 7) + 8 * ((L >> 3) & 3);
    const int row  = (L >> 5) * 8 + (threadIdx.x >> 5);
    const int g    = threadIdx.x & 31;
    const int col0 = g * 4;

    f32x4 S = *(const f32x4*)(S0 + ((size_t)b * NDIM + row) * NDIM + col0);

    const size_t STRIDE = (size_t)BATCH * LDC;
    const float* p0 = C + (size_t)b * LDC;

    f32x4 k_a, q_a, k_b, q_b, k_c, q_c;
    float e_a, wv_a, e_b, wv_b, e_c, wv_c;

    k_a  = *(const f32x4*)(p0 + col0);
    q_a  = *(const f32x4*)(p0 + 2 * NDIM + col0);
    e_a  = p0[3 * NDIM + row];
    wv_a = p0[NDIM + row];
    const float* p1 = p0 + STRIDE;
    k_b  = *(const f32x4*)(p1 + col0);
    q_b  = *(const f32x4*)(p1 + 2 * NDIM + col0);
    e_b  = p1[3 * NDIM + row];
    wv_b = p1[NDIM + row];

    const float* p_pref = p1 + STRIDE;  // t = 2
    float* op = out + (size_t)b * NDIM + row;

    for (int t = 0; t < T_STEPS; ++t) {
        k_c  = *(const f32x4*)(p_pref + col0);
        q_c  = *(const f32x4*)(p_pref + 2 * NDIM + col0);
        e_c  = p_pref[3 * NDIM + row];
        wv_c = p_pref[NDIM + row];
        if (t < T_STEPS - 3) p_pref += STRIDE;

        // S_new = tanh(S + kn*(wv - e*S)); dot = S_new . q
        float dot = 0.0f;
#pragma unroll
        for (int j = 0; j < 4; ++j) {
            float t0  = fmaf(-e_a, S[j], wv_a);
            float pre = fmaf(k_a[j], t0, S[j]);
            S[j] = tanh_fast(pre);
            dot = fmaf(S[j], q_a[j], dot);
        }
        dot = dpp_reduce32(dot);

        if ((threadIdx.x & 31) == 31) {
            float sg = __builtin_amdgcn_rcpf(
                1.0f + __builtin_amdgcn_exp2f(-dot * 1.4426950408889634f));
            *op = dot * dot * sg;
        }
        op += BATCH * NDIM;

        k_a = k_b; q_a = q_b; e_a = e_b; wv_a = wv_b;
        k_b = k_c; q_b = q_c; e_b = e_c; wv_b = wv_c;
    }

    *(f32x4*)(out + (size_t)T_STEPS * BATCH * NDIM
              + ((size_t)b * NDIM + row) * NDIM + col0) = S;
}

extern "C" void kernel_launch(void* const* d_in, const int* in_sizes, int n_in,
                              void* d_out, int out_size, void* d_ws, size_t ws_size,
                              hipStream_t stream) {
    const float* x  = (const float*)d_in[0];
    const float* S0 = (const float*)d_in[1];
    const float* wk = (const float*)d_in[2];
    const float* wv = (const float*)d_in[3];
    const float* wq = (const float*)d_in[4];
    const float* we = (const float*)d_in[5];
    const float* ww = (const float*)d_in[6];
    float* out = (float*)d_out;
    float* C   = (float*)d_ws;  // 41,943,040 B

    gemm_kernel<<<dim3(128, 5), 256, 0, stream>>>(x, wk, wv, wq, we, ww, C);
    knorm_kernel<<<MROWS / 4, 256, 0, stream>>>(C);
    ntm_scan_kernel<<<512, 256, 0, stream>>>(C, S0, out);
}

// Round 8
// 312.574 us; speedup vs baseline: 2.1688x; 1.2687x over previous
//
#include <hip/hip_runtime.h>
#include <hip/hip_bf16.h>

// NTM cell forward: T=512, B=32, D=1024, N=128. All I/O f32.
// gemm (LDS-staged split-bf16 3-MFMA) -> knorm (k-normalize in place, fold
// w*v into v-slot) -> scan (32-lane group per S-row, 4 f32/lane, DPP-tree
// dot-reduce, XCD-affine batches, UNROLL-4 rotation-free depth-2 prefetch).
// ws needs only C: 16384*640*4 = 41,943,040 B.

typedef __attribute__((ext_vector_type(8))) short bf16x8;
typedef __attribute__((ext_vector_type(4))) float f32x4;
typedef __attribute__((ext_vector_type(2))) float f32x2;
typedef __attribute__((ext_vector_type(4))) unsigned short u16x4;

static constexpr int T_STEPS = 512;
static constexpr int BATCH   = 32;
static constexpr int DDIM    = 1024;
static constexpr int NDIM    = 128;
static constexpr int LDC     = 5 * NDIM;         // 640
static constexpr int MROWS   = T_STEPS * BATCH;  // 16384

__device__ __forceinline__ void split2(float v, unsigned short& hi, unsigned short& lo) {
    unsigned u  = __builtin_bit_cast(unsigned, v);
    unsigned uh = u & 0xFFFF0000u;
    hi = (unsigned short)(uh >> 16);
    float d = v - __builtin_bit_cast(float, uh);
    lo = (unsigned short)(__builtin_bit_cast(unsigned, d) >> 16);
}

// ---------------- Phase 1: LDS-staged split-bf16 GEMM (unchanged R5) -------
static constexpr int LSTR = 40;
static constexpr int OAH = 0, OAL = 128 * LSTR, OBH = 2 * 128 * LSTR, OBL = 3 * 128 * LSTR;

__global__ __launch_bounds__(256, 3) void gemm_kernel(
    const float* __restrict__ x,
    const float* __restrict__ w0, const float* __restrict__ w1,
    const float* __restrict__ w2, const float* __restrict__ w3,
    const float* __restrict__ w4,
    float* __restrict__ C)
{
    __shared__ unsigned short lds[4 * 128 * LSTR];  // 40,960 B

    const float* Ws[5] = {w0, w1, w2, w3, w4};
    const int bm = blockIdx.x, bn = blockIdx.y;
    const int tid  = threadIdx.x;
    const int wave = tid >> 6, lane = tid & 63;
    const int quad = lane >> 4, l16 = lane & 15;
    const int wm = (wave >> 1) * 64, wn = (wave & 1) * 64;
    const int m0 = bm * 128;
    const float* wsrc = Ws[bn];

    f32x4 acc[4][4];
#pragma unroll
    for (int i = 0; i < 4; ++i)
#pragma unroll
        for (int j = 0; j < 4; ++j) acc[i][j] = (f32x4)(0.0f);

    const int srow = tid >> 3;
    const int sc4  = tid & 7;
    const int fa = (wm + l16) * LSTR + quad * 8;
    const int fb = (wn + l16) * LSTR + quad * 8;

    for (int kk = 0; kk < 32; ++kk) {
#pragma unroll
        for (int i = 0; i < 4; ++i) {
            const int row = srow + i * 32;
            f32x4 va = *(const f32x4*)(x + (size_t)(m0 + row) * DDIM + kk * 32 + sc4 * 4);
            f32x4 vb = *(const f32x4*)(wsrc + (size_t)row * DDIM + kk * 32 + sc4 * 4);
            u16x4 ha, la, hb, lb;
#pragma unroll
            for (int j = 0; j < 4; ++j) {
                unsigned short h, l;
                split2(va[j], h, l); ha[j] = h; la[j] = l;
                split2(vb[j], h, l); hb[j] = h; lb[j] = l;
            }
            const int o = row * LSTR + sc4 * 4;
            *(u16x4*)&lds[OAH + o] = ha;
            *(u16x4*)&lds[OAL + o] = la;
            *(u16x4*)&lds[OBH + o] = hb;
            *(u16x4*)&lds[OBL + o] = lb;
        }
        __syncthreads();

        bf16x8 ah[4], al[4], bh[4], bl[4];
#pragma unroll
        for (int i = 0; i < 4; ++i) {
            ah[i] = *(const bf16x8*)&lds[OAH + fa + i * 16 * LSTR];
            al[i] = *(const bf16x8*)&lds[OAL + fa + i * 16 * LSTR];
            bh[i] = *(const bf16x8*)&lds[OBH + fb + i * 16 * LSTR];
            bl[i] = *(const bf16x8*)&lds[OBL + fb + i * 16 * LSTR];
        }
#pragma unroll
        for (int mi = 0; mi < 4; ++mi)
#pragma unroll
            for (int ni = 0; ni < 4; ++ni) {
                acc[mi][ni] = __builtin_amdgcn_mfma_f32_16x16x32_bf16(
                    ah[mi], bh[ni], acc[mi][ni], 0, 0, 0);
                acc[mi][ni] = __builtin_amdgcn_mfma_f32_16x16x32_bf16(
                    ah[mi], bl[ni], acc[mi][ni], 0, 0, 0);
                acc[mi][ni] = __builtin_amdgcn_mfma_f32_16x16x32_bf16(
                    al[mi], bh[ni], acc[mi][ni], 0, 0, 0);
            }
        __syncthreads();
    }

#pragma unroll
    for (int mi = 0; mi < 4; ++mi)
#pragma unroll
        for (int ni = 0; ni < 4; ++ni) {
            const int row = m0 + wm + mi * 16 + quad * 4;
            const int col = bn * 128 + wn + ni * 16 + l16;
#pragma unroll
            for (int r = 0; r < 4; ++r)
                C[(size_t)(row + r) * LDC + col] = acc[mi][ni][r];
        }
}

// ---------------- knorm prep (unchanged R5) ----------------
__global__ __launch_bounds__(256) void knorm_kernel(float* __restrict__ C)
{
    const int r    = blockIdx.x * 4 + (threadIdx.x >> 6);
    const int lane = threadIdx.x & 63;
    float* base = C + (size_t)r * LDC;

    f32x2 k2 = *(const f32x2*)(base + lane * 2);
    f32x2 v2 = *(const f32x2*)(base + NDIM + lane * 2);
    f32x2 w2 = *(const f32x2*)(base + 4 * NDIM + lane * 2);

    float ss = k2.x * k2.x + k2.y * k2.y;
#pragma unroll
    for (int off = 32; off >= 1; off >>= 1) ss += __shfl_xor(ss, off, 64);
    float inv = __builtin_amdgcn_rcpf(sqrtf(ss) + 1e-6f);

    f32x2 kn = {k2.x * inv, k2.y * inv};
    f32x2 wv = {v2.x * w2.x, v2.y * w2.y};
    *(f32x2*)(base + lane * 2) = kn;
    *(f32x2*)(base + NDIM + lane * 2) = wv;
}

// ---------------- recurrent scan ----------------
__device__ __forceinline__ float tanh_fast(float xx) {
    float ex = __builtin_amdgcn_exp2f(xx * 2.8853900817779268f);  // e^(2x)
    float r  = __builtin_amdgcn_rcpf(ex + 1.0f);
    return fmaf(-2.0f, r, 1.0f);
}

template <int CTRL, int RMASK>
__device__ __forceinline__ float dpp_add(float x) {
    int yi = __builtin_amdgcn_update_dpp(
        0, __builtin_bit_cast(int, x), CTRL, RMASK, 0xF, true);
    return x + __builtin_bit_cast(float, yi);
}

// Sum across each 32-lane group; valid in lanes 16..31 / 48..63.
__device__ __forceinline__ float dpp_reduce32(float x) {
    x = dpp_add<0xB1,  0xF>(x);  // + lane^1
    x = dpp_add<0x4E,  0xF>(x);  // + lane^2
    x = dpp_add<0x141, 0xF>(x);  // row_half_mirror: + lane^4
    x = dpp_add<0x140, 0xF>(x);  // row_mirror: + lane^8
    x = dpp_add<0x142, 0xA>(x);  // row_bcast15: rows 1,3 += row 0,2 sum
    return x;
}

// Grid 512 x 256; 32-lane group per S-row, 4 f32/lane, 2 rows/wave.
// XCD-affine batches. UNROLL-4 T-loop: step t computes slot t&3 and
// prefetches t+2 into slot (t+2)&3 — no register rotation, so the first use
// of each load is 2 full steps after issue (vmcnt naturally covered).
__global__ __launch_bounds__(256) void ntm_scan_kernel(
    const float* __restrict__ C, const float* __restrict__ S0,
    float* __restrict__ out)
{
    const int L    = blockIdx.x;            // 0..511
    const int b    = (L & 7) + 8 * ((L >> 3) & 3);
    const int row  = (L >> 5) * 8 + (threadIdx.x >> 5);
    const int g    = threadIdx.x & 31;
    const int col0 = g * 4;

    f32x4 S = *(const f32x4*)(S0 + ((size_t)b * NDIM + row) * NDIM + col0);

    const size_t STRIDE = (size_t)BATCH * LDC;  // floats per timestep
    const float* pb = C + (size_t)b * LDC;      // t=0 base for this batch

    f32x4 kS[4], qS[4];
    float eS[4], wvS[4];

#pragma unroll
    for (int s = 0; s < 2; ++s) {  // preload t=0 -> slot0, t=1 -> slot1
        const float* p = pb + (size_t)s * STRIDE;
        kS[s]  = *(const f32x4*)(p + col0);
        qS[s]  = *(const f32x4*)(p + 2 * NDIM + col0);
        eS[s]  = p[3 * NDIM + row];
        wvS[s] = p[NDIM + row];
    }

    float* op = out + (size_t)b * NDIM + row;

    for (int ti = 0; ti < T_STEPS / 4; ++ti) {
#pragma unroll
        for (int j = 0; j < 4; ++j) {
            const int t = ti * 4 + j;
            // prefetch t+2 into slot (j+2)&3 (scalar-uniform base, clamped)
            {
                int tp = t + 2;
                if (tp > T_STEPS - 1) tp = T_STEPS - 1;
                const float* p = pb + (size_t)tp * STRIDE;
                const int ps = (j + 2) & 3;
                kS[ps]  = *(const f32x4*)(p + col0);
                qS[ps]  = *(const f32x4*)(p + 2 * NDIM + col0);
                eS[ps]  = p[3 * NDIM + row];
                wvS[ps] = p[NDIM + row];
            }
            // compute slot j:  S_new = tanh(S + kn*(wv - e*S)); dot = S_new.q
            float dot = 0.0f;
#pragma unroll
            for (int u = 0; u < 4; ++u) {
                float t0  = fmaf(-eS[j], S[u], wvS[j]);
                float pre = fmaf(kS[j][u], t0, S[u]);
                S[u] = tanh_fast(pre);
                dot = fmaf(S[u], qS[j][u], dot);
            }
            dot = dpp_reduce32(dot);

            if ((threadIdx.x & 31) == 31) {
                float sg = __builtin_amdgcn_rcpf(
                    1.0f + __builtin_amdgcn_exp2f(-dot * 1.4426950408889634f));
                op[(size_t)t * BATCH * NDIM] = dot * dot * sg;
            }
        }
    }

    *(f32x4*)(out + (size_t)T_STEPS * BATCH * NDIM
              + ((size_t)b * NDIM + row) * NDIM + col0) = S;
}

extern "C" void kernel_launch(void* const* d_in, const int* in_sizes, int n_in,
                              void* d_out, int out_size, void* d_ws, size_t ws_size,
                              hipStream_t stream) {
    const float* x  = (const float*)d_in[0];
    const float* S0 = (const float*)d_in[1];
    const float* wk = (const float*)d_in[2];
    const float* wv = (const float*)d_in[3];
    const float* wq = (const float*)d_in[4];
    const float* we = (const float*)d_in[5];
    const float* ww = (const float*)d_in[6];
    float* out = (float*)d_out;
    float* C   = (float*)d_ws;  // 41,943,040 B

    gemm_kernel<<<dim3(128, 5), 256, 0, stream>>>(x, wk, wv, wq, we, ww, C);
    knorm_kernel<<<MROWS / 4, 256, 0, stream>>>(C);
    ntm_scan_kernel<<<512, 256, 0, stream>>>(C, S0, out);
}

// Round 9
// 307.922 us; speedup vs baseline: 2.2016x; 1.0151x over previous
//
#include <hip/hip_runtime.h>
#include <hip/hip_bf16.h>

// NTM cell forward: T=512, B=32, D=1024, N=128. All I/O f32.
// gemm (LDS-staged split-bf16 3-MFMA, XCD-affine block swizzle) -> knorm
// (k-normalize in place, fold w*v) -> scan (32-lane group/S-row, 4 f32/lane,
// DPP reduce, unroll-4 depth-2 prefetch, raw-dot store) -> silu epilogue.
// ws needs only C: 16384*640*4 = 41,943,040 B.

typedef __attribute__((ext_vector_type(8))) short bf16x8;
typedef __attribute__((ext_vector_type(4))) float f32x4;
typedef __attribute__((ext_vector_type(2))) float f32x2;
typedef __attribute__((ext_vector_type(4))) unsigned short u16x4;

static constexpr int T_STEPS = 512;
static constexpr int BATCH   = 32;
static constexpr int DDIM    = 1024;
static constexpr int NDIM    = 128;
static constexpr int LDC     = 5 * NDIM;         // 640
static constexpr int MROWS   = T_STEPS * BATCH;  // 16384
static constexpr int OUT_N   = T_STEPS * BATCH * NDIM;  // 2,097,152

__device__ __forceinline__ void split2(float v, unsigned short& hi, unsigned short& lo) {
    unsigned u  = __builtin_bit_cast(unsigned, v);
    unsigned uh = u & 0xFFFF0000u;
    hi = (unsigned short)(uh >> 16);
    float d = v - __builtin_bit_cast(float, uh);
    lo = (unsigned short)(__builtin_bit_cast(unsigned, d) >> 16);
}

// ---------------- Phase 1: LDS-staged split-bf16 GEMM ----------------
// 1D grid 640, XCD-affine swizzle: id = ((bm>>3)*5 + bn)*8 + (bm&7).
// All 5 bn-blocks of one bm (x-tile reuse) and all bm≡r (mod 8) blocks
// (W reuse, 2.5 MB) share one XCD's L2 (round-robin dispatch heuristic).
static constexpr int LSTR = 40;
static constexpr int OAH = 0, OAL = 128 * LSTR, OBH = 2 * 128 * LSTR, OBL = 3 * 128 * LSTR;

__global__ __launch_bounds__(256, 3) void gemm_kernel(
    const float* __restrict__ x,
    const float* __restrict__ w0, const float* __restrict__ w1,
    const float* __restrict__ w2, const float* __restrict__ w3,
    const float* __restrict__ w4,
    float* __restrict__ C)
{
    __shared__ unsigned short lds[4 * 128 * LSTR];  // 40,960 B

    const float* Ws[5] = {w0, w1, w2, w3, w4};
    const int id  = blockIdx.x;
    const int xcd = id & 7;
    const int kq  = id >> 3;        // 0..79
    const int bn  = kq % 5;
    const int bm  = (kq / 5) * 8 + xcd;

    const int tid  = threadIdx.x;
    const int wave = tid >> 6, lane = tid & 63;
    const int quad = lane >> 4, l16 = lane & 15;
    const int wm = (wave >> 1) * 64, wn = (wave & 1) * 64;
    const int m0 = bm * 128;
    const float* wsrc = Ws[bn];

    f32x4 acc[4][4];
#pragma unroll
    for (int i = 0; i < 4; ++i)
#pragma unroll
        for (int j = 0; j < 4; ++j) acc[i][j] = (f32x4)(0.0f);

    const int srow = tid >> 3;
    const int sc4  = tid & 7;
    const int fa = (wm + l16) * LSTR + quad * 8;
    const int fb = (wn + l16) * LSTR + quad * 8;

    for (int kk = 0; kk < 32; ++kk) {
#pragma unroll
        for (int i = 0; i < 4; ++i) {
            const int row = srow + i * 32;
            f32x4 va = *(const f32x4*)(x + (size_t)(m0 + row) * DDIM + kk * 32 + sc4 * 4);
            f32x4 vb = *(const f32x4*)(wsrc + (size_t)row * DDIM + kk * 32 + sc4 * 4);
            u16x4 ha, la, hb, lb;
#pragma unroll
            for (int j = 0; j < 4; ++j) {
                unsigned short h, l;
                split2(va[j], h, l); ha[j] = h; la[j] = l;
                split2(vb[j], h, l); hb[j] = h; lb[j] = l;
            }
            const int o = row * LSTR + sc4 * 4;
            *(u16x4*)&lds[OAH + o] = ha;
            *(u16x4*)&lds[OAL + o] = la;
            *(u16x4*)&lds[OBH + o] = hb;
            *(u16x4*)&lds[OBL + o] = lb;
        }
        __syncthreads();

        bf16x8 ah[4], al[4], bh[4], bl[4];
#pragma unroll
        for (int i = 0; i < 4; ++i) {
            ah[i] = *(const bf16x8*)&lds[OAH + fa + i * 16 * LSTR];
            al[i] = *(const bf16x8*)&lds[OAL + fa + i * 16 * LSTR];
            bh[i] = *(const bf16x8*)&lds[OBH + fb + i * 16 * LSTR];
            bl[i] = *(const bf16x8*)&lds[OBL + fb + i * 16 * LSTR];
        }
#pragma unroll
        for (int mi = 0; mi < 4; ++mi)
#pragma unroll
            for (int ni = 0; ni < 4; ++ni) {
                acc[mi][ni] = __builtin_amdgcn_mfma_f32_16x16x32_bf16(
                    ah[mi], bh[ni], acc[mi][ni], 0, 0, 0);
                acc[mi][ni] = __builtin_amdgcn_mfma_f32_16x16x32_bf16(
                    ah[mi], bl[ni], acc[mi][ni], 0, 0, 0);
                acc[mi][ni] = __builtin_amdgcn_mfma_f32_16x16x32_bf16(
                    al[mi], bh[ni], acc[mi][ni], 0, 0, 0);
            }
        __syncthreads();
    }

#pragma unroll
    for (int mi = 0; mi < 4; ++mi)
#pragma unroll
        for (int ni = 0; ni < 4; ++ni) {
            const int row = m0 + wm + mi * 16 + quad * 4;
            const int col = bn * 128 + wn + ni * 16 + l16;
#pragma unroll
            for (int r = 0; r < 4; ++r)
                C[(size_t)(row + r) * LDC + col] = acc[mi][ni][r];
        }
}

// ---------------- knorm prep ----------------
__global__ __launch_bounds__(256) void knorm_kernel(float* __restrict__ C)
{
    const int r    = blockIdx.x * 4 + (threadIdx.x >> 6);
    const int lane = threadIdx.x & 63;
    float* base = C + (size_t)r * LDC;

    f32x2 k2 = *(const f32x2*)(base + lane * 2);
    f32x2 v2 = *(const f32x2*)(base + NDIM + lane * 2);
    f32x2 w2 = *(const f32x2*)(base + 4 * NDIM + lane * 2);

    float ss = k2.x * k2.x + k2.y * k2.y;
#pragma unroll
    for (int off = 32; off >= 1; off >>= 1) ss += __shfl_xor(ss, off, 64);
    float inv = __builtin_amdgcn_rcpf(sqrtf(ss) + 1e-6f);

    f32x2 kn = {k2.x * inv, k2.y * inv};
    f32x2 wv = {v2.x * w2.x, v2.y * w2.y};
    *(f32x2*)(base + lane * 2) = kn;
    *(f32x2*)(base + NDIM + lane * 2) = wv;
}

// ---------------- recurrent scan ----------------
__device__ __forceinline__ float tanh_fast(float xx) {
    float ex = __builtin_amdgcn_exp2f(xx * 2.8853900817779268f);  // e^(2x)
    float r  = __builtin_amdgcn_rcpf(ex + 1.0f);
    return fmaf(-2.0f, r, 1.0f);
}

template <int CTRL, int RMASK>
__device__ __forceinline__ float dpp_add(float x) {
    int yi = __builtin_amdgcn_update_dpp(
        0, __builtin_bit_cast(int, x), CTRL, RMASK, 0xF, true);
    return x + __builtin_bit_cast(float, yi);
}

// Sum across each 32-lane group; valid in lanes 16..31 / 48..63.
__device__ __forceinline__ float dpp_reduce32(float x) {
    x = dpp_add<0xB1,  0xF>(x);  // + lane^1
    x = dpp_add<0x4E,  0xF>(x);  // + lane^2
    x = dpp_add<0x141, 0xF>(x);  // row_half_mirror: + lane^4
    x = dpp_add<0x140, 0xF>(x);  // row_mirror: + lane^8
    x = dpp_add<0x142, 0xA>(x);  // row_bcast15: rows 1,3 += row 0,2 sum
    return x;
}

// Grid 512 x 256; 32-lane group per S-row, 4 f32/lane, 2 rows/wave.
// XCD-affine batches; unroll-4 rotation-free depth-2 prefetch.
// Stores RAW dot (silu applied by epilogue kernel).
__global__ __launch_bounds__(256) void ntm_scan_kernel(
    const float* __restrict__ C, const float* __restrict__ S0,
    float* __restrict__ out)
{
    const int L    = blockIdx.x;            // 0..511
    const int b    = (L & 7) + 8 * ((L >> 3) & 3);
    const int row  = (L >> 5) * 8 + (threadIdx.x >> 5);
    const int g    = threadIdx.x & 31;
    const int col0 = g * 4;

    f32x4 S = *(const f32x4*)(S0 + ((size_t)b * NDIM + row) * NDIM + col0);

    const size_t STRIDE = (size_t)BATCH * LDC;
    const float* pb = C + (size_t)b * LDC;

    f32x4 kS[4], qS[4];
    float eS[4], wvS[4];

#pragma unroll
    for (int s = 0; s < 2; ++s) {
        const float* p = pb + (size_t)s * STRIDE;
        kS[s]  = *(const f32x4*)(p + col0);
        qS[s]  = *(const f32x4*)(p + 2 * NDIM + col0);
        eS[s]  = p[3 * NDIM + row];
        wvS[s] = p[NDIM + row];
    }

    float* op = out + (size_t)b * NDIM + row;

    for (int ti = 0; ti < T_STEPS / 4; ++ti) {
#pragma unroll
        for (int j = 0; j < 4; ++j) {
            const int t = ti * 4 + j;
            {
                int tp = t + 2;
                if (tp > T_STEPS - 1) tp = T_STEPS - 1;
                const float* p = pb + (size_t)tp * STRIDE;
                const int ps = (j + 2) & 3;
                kS[ps]  = *(const f32x4*)(p + col0);
                qS[ps]  = *(const f32x4*)(p + 2 * NDIM + col0);
                eS[ps]  = p[3 * NDIM + row];
                wvS[ps] = p[NDIM + row];
            }
            float dot = 0.0f;
#pragma unroll
            for (int u = 0; u < 4; ++u) {
                float t0  = fmaf(-eS[j], S[u], wvS[j]);
                float pre = fmaf(kS[j][u], t0, S[u]);
                S[u] = tanh_fast(pre);
                dot = fmaf(S[u], qS[j][u], dot);
            }
            dot = dpp_reduce32(dot);

            if ((threadIdx.x & 31) == 31)
                op[(size_t)t * BATCH * NDIM] = dot;  // raw; silu in epilogue
        }
    }

    *(f32x4*)(out + (size_t)T_STEPS * BATCH * NDIM
              + ((size_t)b * NDIM + row) * NDIM + col0) = S;
}

// ---------------- silu epilogue: y = d^2 * sigmoid(d) over out[0:OUT_N] ----
__global__ __launch_bounds__(256) void silu_kernel(float* __restrict__ out)
{
    const int i = blockIdx.x * 256 + threadIdx.x;  // f32x4 index
    f32x4 d = ((const f32x4*)out)[i];
    f32x4 y;
#pragma unroll
    for (int j = 0; j < 4; ++j) {
        float sg = __builtin_amdgcn_rcpf(
            1.0f + __builtin_amdgcn_exp2f(-d[j] * 1.4426950408889634f));
        y[j] = d[j] * d[j] * sg;
    }
    ((f32x4*)out)[i] = y;
}

extern "C" void kernel_launch(void* const* d_in, const int* in_sizes, int n_in,
                              void* d_out, int out_size, void* d_ws, size_t ws_size,
                              hipStream_t stream) {
    const float* x  = (const float*)d_in[0];
    const float* S0 = (const float*)d_in[1];
    const float* wk = (const float*)d_in[2];
    const float* wv = (const float*)d_in[3];
    const float* wq = (const float*)d_in[4];
    const float* we = (const float*)d_in[5];
    const float* ww = (const float*)d_in[6];
    float* out = (float*)d_out;
    float* C   = (float*)d_ws;  // 41,943,040 B

    gemm_kernel<<<640, 256, 0, stream>>>(x, wk, wv, wq, we, ww, C);
    knorm_kernel<<<MROWS / 4, 256, 0, stream>>>(C);
    ntm_scan_kernel<<<512, 256, 0, stream>>>(C, S0, out);
    silu_kernel<<<OUT_N / 1024, 256, 0, stream>>>(out);
}

// Round 10
// 297.312 us; speedup vs baseline: 2.2802x; 1.0357x over previous
//
#include <hip/hip_runtime.h>
#include <hip/hip_bf16.h>

// NTM cell forward: T=512, B=32, D=1024, N=128. All I/O f32.
// gemm (LDS-staged split-bf16 3-MFMA, cross-kk global->reg prefetch) ->
// knorm (k-normalize in place, fold w*v) -> scan (32-lane group/S-row,
// DPP reduce, unroll-4 depth-2 prefetch, raw-dot store) -> silu epilogue.
// ws needs only C: 16384*640*4 = 41,943,040 B.

typedef __attribute__((ext_vector_type(8))) short bf16x8;
typedef __attribute__((ext_vector_type(4))) float f32x4;
typedef __attribute__((ext_vector_type(2))) float f32x2;
typedef __attribute__((ext_vector_type(4))) unsigned short u16x4;

static constexpr int T_STEPS = 512;
static constexpr int BATCH   = 32;
static constexpr int DDIM    = 1024;
static constexpr int NDIM    = 128;
static constexpr int LDC     = 5 * NDIM;         // 640
static constexpr int MROWS   = T_STEPS * BATCH;  // 16384
static constexpr int OUT_N   = T_STEPS * BATCH * NDIM;  // 2,097,152

__device__ __forceinline__ void split2(float v, unsigned short& hi, unsigned short& lo) {
    unsigned u  = __builtin_bit_cast(unsigned, v);
    unsigned uh = u & 0xFFFF0000u;
    hi = (unsigned short)(uh >> 16);
    float d = v - __builtin_bit_cast(float, uh);
    lo = (unsigned short)(__builtin_bit_cast(unsigned, d) >> 16);
}

// ---------------- Phase 1: LDS-staged split-bf16 GEMM ----------------
// 1D grid 640, XCD-affine swizzle (kept from R9 — harmless).
// kk-loop pipeline: split/write(kk) | barrier | prefetch loads(kk+1) |
// ds_read + 48 MFMA | barrier.  Stage registers die at the split and are
// reloaded in place -> no rotation movs; the vmcnt wait for the prefetch
// lands at the NEXT split, covered by this iteration's MFMA phase.
static constexpr int LSTR = 40;
static constexpr int OAH = 0, OAL = 128 * LSTR, OBH = 2 * 128 * LSTR, OBL = 3 * 128 * LSTR;

__global__ __launch_bounds__(256, 3) void gemm_kernel(
    const float* __restrict__ x,
    const float* __restrict__ w0, const float* __restrict__ w1,
    const float* __restrict__ w2, const float* __restrict__ w3,
    const float* __restrict__ w4,
    float* __restrict__ C)
{
    __shared__ unsigned short lds[4 * 128 * LSTR];  // 40,960 B

    const float* Ws[5] = {w0, w1, w2, w3, w4};
    const int id  = blockIdx.x;
    const int xcd = id & 7;
    const int kq  = id >> 3;        // 0..79
    const int bn  = kq % 5;
    const int bm  = (kq / 5) * 8 + xcd;

    const int tid  = threadIdx.x;
    const int wave = tid >> 6, lane = tid & 63;
    const int quad = lane >> 4, l16 = lane & 15;
    const int wm = (wave >> 1) * 64, wn = (wave & 1) * 64;
    const int m0 = bm * 128;
    const float* wsrc = Ws[bn];

    f32x4 acc[4][4];
#pragma unroll
    for (int i = 0; i < 4; ++i)
#pragma unroll
        for (int j = 0; j < 4; ++j) acc[i][j] = (f32x4)(0.0f);

    const int srow = tid >> 3;      // 0..31
    const int sc4  = tid & 7;       // 16B chunk
    const int fa = (wm + l16) * LSTR + quad * 8;
    const int fb = (wn + l16) * LSTR + quad * 8;

    // per-thread global base pointers (row fixed, col = kk*32 + sc4*4)
    const float* xp[4];
    const float* wp[4];
#pragma unroll
    for (int i = 0; i < 4; ++i) {
        xp[i] = x    + (size_t)(m0 + srow + i * 32) * DDIM + sc4 * 4;
        wp[i] = wsrc + (size_t)(srow + i * 32) * DDIM + sc4 * 4;
    }

    // preload kk = 0
    f32x4 ra[4], rb[4];
#pragma unroll
    for (int i = 0; i < 4; ++i) { ra[i] = *(const f32x4*)xp[i]; rb[i] = *(const f32x4*)wp[i]; }

    for (int kk = 0; kk < 32; ++kk) {
        // ---- stage: split current regs -> LDS (regs die here) ----
#pragma unroll
        for (int i = 0; i < 4; ++i) {
            u16x4 ha, la, hb, lb;
#pragma unroll
            for (int j = 0; j < 4; ++j) {
                unsigned short h, l;
                split2(ra[i][j], h, l); ha[j] = h; la[j] = l;
                split2(rb[i][j], h, l); hb[j] = h; lb[j] = l;
            }
            const int o = (srow + i * 32) * LSTR + sc4 * 4;
            *(u16x4*)&lds[OAH + o] = ha;
            *(u16x4*)&lds[OAL + o] = la;
            *(u16x4*)&lds[OBH + o] = hb;
            *(u16x4*)&lds[OBL + o] = lb;
        }
        __syncthreads();

        // ---- prefetch kk+1 into the same regs (clamped reload at end) ----
        const int kn = (kk + 1 < 32) ? kk + 1 : 31;
#pragma unroll
        for (int i = 0; i < 4; ++i) {
            ra[i] = *(const f32x4*)(xp[i] + kn * 32);
            rb[i] = *(const f32x4*)(wp[i] + kn * 32);
        }

        // ---- compute: phased frag reads to bound register pressure ----
        bf16x8 ah[4], bh[4];
#pragma unroll
        for (int i = 0; i < 4; ++i) {
            ah[i] = *(const bf16x8*)&lds[OAH + fa + i * 16 * LSTR];
            bh[i] = *(const bf16x8*)&lds[OBH + fb + i * 16 * LSTR];
        }
#pragma unroll
        for (int mi = 0; mi < 4; ++mi)
#pragma unroll
            for (int ni = 0; ni < 4; ++ni)
                acc[mi][ni] = __builtin_amdgcn_mfma_f32_16x16x32_bf16(
                    ah[mi], bh[ni], acc[mi][ni], 0, 0, 0);
        {
            bf16x8 bl[4];
#pragma unroll
            for (int i = 0; i < 4; ++i)
                bl[i] = *(const bf16x8*)&lds[OBL + fb + i * 16 * LSTR];
#pragma unroll
            for (int mi = 0; mi < 4; ++mi)
#pragma unroll
                for (int ni = 0; ni < 4; ++ni)
                    acc[mi][ni] = __builtin_amdgcn_mfma_f32_16x16x32_bf16(
                        ah[mi], bl[ni], acc[mi][ni], 0, 0, 0);
        }
        {
            bf16x8 al[4];
#pragma unroll
            for (int i = 0; i < 4; ++i)
                al[i] = *(const bf16x8*)&lds[OAL + fa + i * 16 * LSTR];
#pragma unroll
            for (int mi = 0; mi < 4; ++mi)
#pragma unroll
                for (int ni = 0; ni < 4; ++ni)
                    acc[mi][ni] = __builtin_amdgcn_mfma_f32_16x16x32_bf16(
                        al[mi], bh[ni], acc[mi][ni], 0, 0, 0);
        }
        __syncthreads();
    }

#pragma unroll
    for (int mi = 0; mi < 4; ++mi)
#pragma unroll
        for (int ni = 0; ni < 4; ++ni) {
            const int row = m0 + wm + mi * 16 + quad * 4;
            const int col = bn * 128 + wn + ni * 16 + l16;
#pragma unroll
            for (int r = 0; r < 4; ++r)
                C[(size_t)(row + r) * LDC + col] = acc[mi][ni][r];
        }
}

// ---------------- knorm prep ----------------
__global__ __launch_bounds__(256) void knorm_kernel(float* __restrict__ C)
{
    const int r    = blockIdx.x * 4 + (threadIdx.x >> 6);
    const int lane = threadIdx.x & 63;
    float* base = C + (size_t)r * LDC;

    f32x2 k2 = *(const f32x2*)(base + lane * 2);
    f32x2 v2 = *(const f32x2*)(base + NDIM + lane * 2);
    f32x2 w2 = *(const f32x2*)(base + 4 * NDIM + lane * 2);

    float ss = k2.x * k2.x + k2.y * k2.y;
#pragma unroll
    for (int off = 32; off >= 1; off >>= 1) ss += __shfl_xor(ss, off, 64);
    float inv = __builtin_amdgcn_rcpf(sqrtf(ss) + 1e-6f);

    f32x2 kn = {k2.x * inv, k2.y * inv};
    f32x2 wv = {v2.x * w2.x, v2.y * w2.y};
    *(f32x2*)(base + lane * 2) = kn;
    *(f32x2*)(base + NDIM + lane * 2) = wv;
}

// ---------------- recurrent scan ----------------
__device__ __forceinline__ float tanh_fast(float xx) {
    float ex = __builtin_amdgcn_exp2f(xx * 2.8853900817779268f);  // e^(2x)
    float r  = __builtin_amdgcn_rcpf(ex + 1.0f);
    return fmaf(-2.0f, r, 1.0f);
}

template <int CTRL, int RMASK>
__device__ __forceinline__ float dpp_add(float x) {
    int yi = __builtin_amdgcn_update_dpp(
        0, __builtin_bit_cast(int, x), CTRL, RMASK, 0xF, true);
    return x + __builtin_bit_cast(float, yi);
}

// Sum across each 32-lane group; valid in lanes 16..31 / 48..63.
__device__ __forceinline__ float dpp_reduce32(float x) {
    x = dpp_add<0xB1,  0xF>(x);  // + lane^1
    x = dpp_add<0x4E,  0xF>(x);  // + lane^2
    x = dpp_add<0x141, 0xF>(x);  // row_half_mirror: + lane^4
    x = dpp_add<0x140, 0xF>(x);  // row_mirror: + lane^8
    x = dpp_add<0x142, 0xA>(x);  // row_bcast15: rows 1,3 += row 0,2 sum
    return x;
}

// Grid 512 x 256; 32-lane group per S-row, 4 f32/lane, 2 rows/wave.
// XCD-affine batches; unroll-4 rotation-free depth-2 prefetch; raw-dot store.
__global__ __launch_bounds__(256) void ntm_scan_kernel(
    const float* __restrict__ C, const float* __restrict__ S0,
    float* __restrict__ out)
{
    const int L    = blockIdx.x;            // 0..511
    const int b    = (L & 7) + 8 * ((L >> 3) & 3);
    const int row  = (L >> 5) * 8 + (threadIdx.x >> 5);
    const int g    = threadIdx.x & 31;
    const int col0 = g * 4;

    f32x4 S = *(const f32x4*)(S0 + ((size_t)b * NDIM + row) * NDIM + col0);

    const size_t STRIDE = (size_t)BATCH * LDC;
    const float* pb = C + (size_t)b * LDC;

    f32x4 kS[4], qS[4];
    float eS[4], wvS[4];

#pragma unroll
    for (int s = 0; s < 2; ++s) {
        const float* p = pb + (size_t)s * STRIDE;
        kS[s]  = *(const f32x4*)(p + col0);
        qS[s]  = *(const f32x4*)(p + 2 * NDIM + col0);
        eS[s]  = p[3 * NDIM + row];
        wvS[s] = p[NDIM + row];
    }

    float* op = out + (size_t)b * NDIM + row;

    for (int ti = 0; ti < T_STEPS / 4; ++ti) {
#pragma unroll
        for (int j = 0; j < 4; ++j) {
            const int t = ti * 4 + j;
            {
                int tp = t + 2;
                if (tp > T_STEPS - 1) tp = T_STEPS - 1;
                const float* p = pb + (size_t)tp * STRIDE;
                const int ps = (j + 2) & 3;
                kS[ps]  = *(const f32x4*)(p + col0);
                qS[ps]  = *(const f32x4*)(p + 2 * NDIM + col0);
                eS[ps]  = p[3 * NDIM + row];
                wvS[ps] = p[NDIM + row];
            }
            float dot = 0.0f;
#pragma unroll
            for (int u = 0; u < 4; ++u) {
                float t0  = fmaf(-eS[j], S[u], wvS[j]);
                float pre = fmaf(kS[j][u], t0, S[u]);
                S[u] = tanh_fast(pre);
                dot = fmaf(S[u], qS[j][u], dot);
            }
            dot = dpp_reduce32(dot);

            if ((threadIdx.x & 31) == 31)
                op[(size_t)t * BATCH * NDIM] = dot;  // raw; silu in epilogue
        }
    }

    *(f32x4*)(out + (size_t)T_STEPS * BATCH * NDIM
              + ((size_t)b * NDIM + row) * NDIM + col0) = S;
}

// ---------------- silu epilogue: y = d^2 * sigmoid(d) over out[0:OUT_N] ----
__global__ __launch_bounds__(256) void silu_kernel(float* __restrict__ out)
{
    const int i = blockIdx.x * 256 + threadIdx.x;  // f32x4 index
    f32x4 d = ((const f32x4*)out)[i];
    f32x4 y;
#pragma unroll
    for (int j = 0; j < 4; ++j) {
        float sg = __builtin_amdgcn_rcpf(
            1.0f + __builtin_amdgcn_exp2f(-d[j] * 1.4426950408889634f));
        y[j] = d[j] * d[j] * sg;
    }
    ((f32x4*)out)[i] = y;
}

extern "C" void kernel_launch(void* const* d_in, const int* in_sizes, int n_in,
                              void* d_out, int out_size, void* d_ws, size_t ws_size,
                              hipStream_t stream) {
    const float* x  = (const float*)d_in[0];
    const float* S0 = (const float*)d_in[1];
    const float* wk = (const float*)d_in[2];
    const float* wv = (const float*)d_in[3];
    const float* wq = (const float*)d_in[4];
    const float* we = (const float*)d_in[5];
    const float* ww = (const float*)d_in[6];
    float* out = (float*)d_out;
    float* C   = (float*)d_ws;  // 41,943,040 B

    gemm_kernel<<<640, 256, 0, stream>>>(x, wk, wv, wq, we, ww, C);
    knorm_kernel<<<MROWS / 4, 256, 0, stream>>>(C);
    ntm_scan_kernel<<<512, 256, 0, stream>>>(C, S0, out);
    silu_kernel<<<OUT_N / 1024, 256, 0, stream>>>(out);
}